// Round 12
// baseline (215.709 us; speedup 1.0000x reference)
//
#include <hip/hip_runtime.h>
#include <math.h>

#define KDIM 128
#define TLEN 512
#define BATCH 16
#define CH_L 16
#define NCH 32           // chunks per batch (replay)
#define NMAT 31          // chunk matrices: chunk c covers t in [16c+1, 16c+16]

typedef _Float16 half8 __attribute__((ext_vector_type(8)));
typedef _Float16 half4 __attribute__((ext_vector_type(4)));
typedef _Float16 half2t __attribute__((ext_vector_type(2)));
typedef float floatx4 __attribute__((ext_vector_type(4)));

#if defined(__has_builtin)
#if __has_builtin(__builtin_amdgcn_fdot2)
#define HAVE_FDOT2 1
#endif
#endif

static __device__ __forceinline__ float dot2f(half2t a, half2t b, float c) {
#ifdef HAVE_FDOT2
    return __builtin_amdgcn_fdot2(a, b, c, false);
#else
    return fmaf((float)a[0], (float)b[0], fmaf((float)a[1], (float)b[1], c));
#endif
}

// ---------------- ws layout (bytes) ----------------
// PST : f16 [BATCH][NMAT] chunks; chunk layout: 16B unit u = K*128 + j holds
//       P[enter=K*8+e][exit=j], e=0..7
#define WS_PST   0
#define WS_SLOG  16252928
#define WS_AENT  16254912
#define WS_NEED  16517056

// Frag conventions (validated R2-R11):
//  A-frag tile(mt,kt): lane(quad,lm) holds A[mt*16+lm][kt*32+quad*8 .. +8]
//  B-frag tile(kt,nt): lane(quad,lm) holds B[kt*32+quad*8 .. +8][nt*16+lm]
//  C/D  tile(mt,nt):   lane(quad,lm) reg q = C[mt*16+quad*4+q][nt*16+lm]
//  padded B layout halfs: bofs(k,n) = ((n>>4)*16 + (k>>3))*136 + (n&15)*8 + (k&7)
// E is UNSHIFTED exp(trans) (|trans|<~4.7 -> E in [9e-3,110], f16-safe; R11-validated).
// S bookkeeping: S = sum(mE) + sum(log rr).

// ================= kernel 1: chunk products, n-partitioned waves ===============
// Wave w owns n-tiles {2w, 2w+1} and ALL m-tiles -> per-iter LDS B-reads drop
// 32->8 b128 per wave (4x). EA (E^T) for all 8 m-tiles lives in 128 VGPRs.
__global__ __launch_bounds__(256, 2) void crf_chunkmat5(
    const float* __restrict__ trans, const float* __restrict__ em,
    _Float16* __restrict__ Pst, float* __restrict__ Sout)
{
    const int c = blockIdx.x;     // 0..NMAT-1
    const int b = blockIdx.y;
    const int tid = threadIdx.x;
    const int w = tid >> 6, lane = tid & 63;
    const int quad = lane >> 4, lm = lane & 15;

    __shared__ __align__(16) _Float16 buf[17408];   // 34.8 KB padded B-layout
    __shared__ __align__(16) float gAll[16 * KDIM]; // 8 KB
    __shared__ float mE[16];
    __shared__ float slotV[4];

    const int t0 = c * CH_L + 1;
    const float* emb = em + (size_t)b * TLEN * KDIM;

    // --- A fragments for ALL m-tiles: EA[mt][kt][i] = E[k][m] = exp(trans[k*128+m])
    //     m = mt*16+lm, k = kt*32+quad*8+i.  128 VGPRs, loop-invariant.
    half8 EA[8][4];
    #pragma unroll
    for (int mt = 0; mt < 8; ++mt) {
        const int m = mt * 16 + lm;
        #pragma unroll
        for (int kt = 0; kt < 4; ++kt) {
            #pragma unroll
            for (int i = 0; i < 8; ++i) {
                EA[mt][kt][i] = (_Float16)__expf(trans[(kt * 32 + quad * 8 + i) * KDIM + m]);
            }
        }
    }

    // --- stage all 16 em rows for this chunk ---
    #pragma unroll
    for (int s = 0; s < 2; ++s) {
        int i4 = tid + s * 256;
        *(float4*)&gAll[i4 * 4] = *(const float4*)&emb[t0 * KDIM + i4 * 4];
    }
    __syncthreads();

    // --- per-row maxes ---
    #pragma unroll
    for (int r2 = 0; r2 < 4; ++r2) {
        const int r = w * 4 + r2;
        float v = fmaxf(gAll[r * KDIM + lane], gAll[r * KDIM + 64 + lane]);
        #pragma unroll
        for (int o = 32; o; o >>= 1) v = fmaxf(v, __shfl_xor(v, o));
        if (lane == 0) mE[r] = v;
    }
    __syncthreads();

    // --- g in place ---
    #pragma unroll
    for (int s = 0; s < 8; ++s) {
        int idx = tid + s * 256;
        gAll[idx] = __expf(gAll[idx] - mE[idx >> 7]);
    }
    __syncthreads();

    // --- init buf = diag(g0)*E^T directly from trans ---
    for (int s = 0; s < 8; ++s) {
        int g = tid + s * 256;
        int row = g >> 4, nl = g & 15;
        int addr = row * 136 + nl * 8;
        int koct = row & 15;
        int n = (row >> 4) * 16 + nl;
        int j0 = koct * 8;
        const float* tr_ = &trans[n * KDIM + j0];
        const float* g0p = &gAll[j0];
        half8 o;
        #pragma unroll
        for (int x = 0; x < 8; ++x) o[x] = (_Float16)(__expf(tr_[x]) * g0p[x]);
        *(half8*)&buf[addr] = o;
    }
    float S = 0.f;
    if (tid == 0) {
        #pragma unroll
        for (int r = 0; r < 16; ++r) S += mE[r];
    }
    __syncthreads();

    const int nt0 = 2 * w, nt1 = 2 * w + 1;
    floatx4 acc[8][2];

    for (int it = 1; it < 16; ++it) {
        #pragma unroll
        for (int mt = 0; mt < 8; ++mt) {
            acc[mt][0] = (floatx4){0.f, 0.f, 0.f, 0.f};
            acc[mt][1] = (floatx4){0.f, 0.f, 0.f, 0.f};
        }

        // ---- C = E^T * Pt, only n-tiles nt0,nt1: 8 b128 B-reads per wave ----
        #pragma unroll
        for (int kt = 0; kt < 4; ++kt) {
            const half8 bb0 = *(const half8*)&buf[(nt0 * 16 + kt * 4 + quad) * 136 + lm * 8];
            const half8 bb1 = *(const half8*)&buf[(nt1 * 16 + kt * 4 + quad) * 136 + lm * 8];
            #pragma unroll
            for (int mt = 0; mt < 8; ++mt) {
                acc[mt][0] = __builtin_amdgcn_mfma_f32_16x16x32_f16(EA[mt][kt], bb0, acc[mt][0], 0, 0, 0);
                acc[mt][1] = __builtin_amdgcn_mfma_f32_16x16x32_f16(EA[mt][kt], bb1, acc[mt][1], 0, 0, 0);
            }
        }

        // row-scale g: row of C = m = mt*16 + quad*4 + q
        const float* gc = &gAll[it * KDIM];
        float lmax = 0.f;
        #pragma unroll
        for (int mt = 0; mt < 8; ++mt) {
            const float4 gr = *(const float4*)&gc[mt * 16 + quad * 4];
            const floatx4 v0 = acc[mt][0], v1 = acc[mt][1];
            float a0 = fmaxf(fmaxf(v0.x * gr.x, v0.y * gr.y), fmaxf(v0.z * gr.z, v0.w * gr.w));
            float a1 = fmaxf(fmaxf(v1.x * gr.x, v1.y * gr.y), fmaxf(v1.z * gr.z, v1.w * gr.w));
            lmax = fmaxf(lmax, fmaxf(a0, a1));
        }
        #pragma unroll
        for (int o = 32; o; o >>= 1) lmax = fmaxf(lmax, __shfl_xor(lmax, o));
        if (lane == 0) slotV[w] = lmax;
        __syncthreads();                                   // barrier 1

        const float rr = fmaxf(fmaxf(slotV[0], slotV[1]), fmaxf(slotV[2], slotV[3]));
        const float rinv = 1.0f / rr;
        if (tid == 0) S += __logf(rr);

        // writeback: new buf(k=m, n) ; m>>3 = mt*2+(quad>>1), m&7 = (quad&1)*4+q
        const int jlb = (quad & 1) * 4;
        #pragma unroll
        for (int mt = 0; mt < 8; ++mt) {
            const float4 gr = *(const float4*)&gc[mt * 16 + quad * 4];
            const float4 sc = {gr.x * rinv, gr.y * rinv, gr.z * rinv, gr.w * rinv};
            const int kh = mt * 2 + (quad >> 1);
            #pragma unroll
            for (int r = 0; r < 2; ++r) {
                const int nt = r ? nt1 : nt0;
                const floatx4 v = acc[mt][r];
                half4 o;
                o[0] = (_Float16)(v.x * sc.x);
                o[1] = (_Float16)(v.y * sc.y);
                o[2] = (_Float16)(v.z * sc.z);
                o[3] = (_Float16)(v.w * sc.w);
                *(half4*)&buf[(nt * 16 + kh) * 136 + lm * 8 + jlb] = o;
            }
        }
        __syncthreads();                                   // barrier 2
    }

    _Float16* Pc = Pst + ((size_t)(b * NMAT + c)) * 16384;
    for (int s = 0; s < 8; ++s) {
        int u = tid + s * 256;
        int K = u >> 7, j = u & 127;
        const int base = ((K >> 1) * 16 + (j >> 3)) * 136 + (j & 7);
        const int eoff = (K & 1) * 64;
        half8 v;
        #pragma unroll
        for (int e = 0; e < 8; ++e) v[e] = buf[base + eoff + e * 8];
        *(half8*)&Pc[u * 8] = v;
    }
    if (tid == 0) Sout[b * NMAT + c] = S;
}

// ================= kernel 2: scanw — one wave per batch, barrier-free (R10) ====
__global__ __launch_bounds__(64, 1) void crf_scanw(
    const float* __restrict__ em, const _Float16* __restrict__ Pst,
    const float* __restrict__ S, float* __restrict__ aEnter)
{
    const int b = blockIdx.x;
    const int lane = threadIdx.x;
    const int j0 = 2 * lane;

    __shared__ __align__(16) _Float16 pbuf[KDIM];
    __shared__ float Sl[NMAT];

    const _Float16* Pb = Pst + (size_t)b * NMAT * 16384;
    float* aeb = aEnter + (size_t)b * NCH * KDIM;

    if (lane < NMAT) Sl[lane] = S[b * NMAT + lane];

    float2 a0 = *(const float2*)&em[(size_t)b * TLEN * KDIM + j0];
    float mx = fmaxf(a0.x, a0.y);
    #pragma unroll
    for (int o = 32; o; o >>= 1) mx = fmaxf(mx, __shfl_xor(mx, o));
    float L = mx;
    *(float2*)&aeb[j0] = a0;
    {
        half2t p2;
        p2[0] = (_Float16)__expf(a0.x - L);
        p2[1] = (_Float16)__expf(a0.y - L);
        ((half2t*)pbuf)[lane] = p2;
    }

    half8 PA[2][16], PB[2][16];
    {
        const _Float16* Pc = Pb;
        #pragma unroll
        for (int K = 0; K < 16; ++K) {
            PA[0][K] = *(const half8*)&Pc[(K * 128 + j0) * 8];
            PA[1][K] = *(const half8*)&Pc[(K * 128 + j0) * 8 + 8];
        }
    }

    auto step = [&](const half8 (&P)[2][16], int c) {
        float q0 = 0.f, q1 = 0.f;
        #pragma unroll
        for (int K = 0; K < 16; ++K) {
            const float4 w = *(const float4*)&pbuf[K * 8];
            const half2t pw0 = __builtin_bit_cast(half2t, w.x);
            const half2t pw1 = __builtin_bit_cast(half2t, w.y);
            const half2t pw2 = __builtin_bit_cast(half2t, w.z);
            const half2t pw3 = __builtin_bit_cast(half2t, w.w);
            const half2t* c0 = (const half2t*)&P[0][K];
            const half2t* c1 = (const half2t*)&P[1][K];
            q0 = dot2f(pw0, c0[0], q0); q0 = dot2f(pw1, c0[1], q0);
            q0 = dot2f(pw2, c0[2], q0); q0 = dot2f(pw3, c0[3], q0);
            q1 = dot2f(pw0, c1[0], q1); q1 = dot2f(pw1, c1[1], q1);
            q1 = dot2f(pw2, c1[2], q1); q1 = dot2f(pw3, c1[3], q1);
        }
        const float s_c = Sl[c];
        const float sigma = __shfl(q0, 0);
        const float base = L + s_c;
        float2 st;
        st.x = base + __logf(q0);
        st.y = base + __logf(q1);
        *(float2*)&aeb[(c + 1) * KDIM + j0] = st;
        const float ri = 1.0f / sigma;
        half2t p2;
        p2[0] = (_Float16)(q0 * ri);
        p2[1] = (_Float16)(q1 * ri);
        ((half2t*)pbuf)[lane] = p2;
        L = base + __logf(sigma);
    };

    for (int c = 0; c < NMAT; c += 2) {
        if (c + 1 < NMAT) {
            const _Float16* Pc = Pb + (size_t)(c + 1) * 16384;
            #pragma unroll
            for (int K = 0; K < 16; ++K) {
                PB[0][K] = *(const half8*)&Pc[(K * 128 + j0) * 8];
                PB[1][K] = *(const half8*)&Pc[(K * 128 + j0) * 8 + 8];
            }
        }
        step(PA, c);
        if (c + 1 < NMAT) {
            if (c + 2 < NMAT) {
                const _Float16* Pc = Pb + (size_t)(c + 2) * 16384;
                #pragma unroll
                for (int K = 0; K < 16; ++K) {
                    PA[0][K] = *(const half8*)&Pc[(K * 128 + j0) * 8];
                    PA[1][K] = *(const half8*)&Pc[(K * 128 + j0) * 8 + 8];
                }
            }
            step(PB, c + 1);
        }
    }
}

// ================= kernel 3: replayw — one wave per (chunk,batch) (R10) ========
__global__ __launch_bounds__(64, 1) void crf_replayw(
    const float* __restrict__ trans, const float* __restrict__ em,
    const int* __restrict__ seq_lens, const float* __restrict__ aEnter,
    float* __restrict__ alpha, float* __restrict__ logZ)
{
    const int c = blockIdx.x, b = blockIdx.y;
    const int l = threadIdx.x;

    __shared__ __align__(16) _Float16 pbuf[KDIM];

    half2t Ea[64], Eb[64];
    #pragma unroll
    for (int t2 = 0; t2 < 64; ++t2) {
        const float* r0 = &trans[(2 * t2) * KDIM];
        const float* r1 = &trans[(2 * t2 + 1) * KDIM];
        half2t ea, eb;
        ea[0] = (_Float16)__expf(r0[l]);
        ea[1] = (_Float16)__expf(r1[l]);
        eb[0] = (_Float16)__expf(r0[l + 64]);
        eb[1] = (_Float16)__expf(r1[l + 64]);
        Ea[t2] = ea;
        Eb[t2] = eb;
    }

    const int len = seq_lens[b];
    const float* emb = em + (size_t)b * TLEN * KDIM;
    float* outb = alpha + (size_t)b * TLEN * KDIM;
    const float* ae = aEnter + ((size_t)b * NCH + c) * KDIM;

    float a0 = ae[l], a1 = ae[l + 64];
    if (c == 0) {
        a0 = emb[l];
        a1 = emb[l + 64];
    }
    float mx = fmaxf(a0, a1);
    #pragma unroll
    for (int o = 32; o; o >>= 1) mx = fmaxf(mx, __shfl_xor(mx, o));
    float L = mx;
    pbuf[l]      = (_Float16)__expf(a0 - L);
    pbuf[l + 64] = (_Float16)__expf(a1 - L);

    float la0 = 0.f, la1 = -INFINITY;
    if (c == 0) {
        outb[l] = a0;
        outb[l + 64] = a1;
        if (len == 1) { la0 = a0; la1 = a1; }
    }

    const int t_begin = c * CH_L + 1;
    const int t_end = (c == NCH - 1) ? (TLEN - 1) : (c * CH_L + CH_L);

    float e0 = emb[t_begin * KDIM + l];
    float e1 = emb[t_begin * KDIM + l + 64];

    for (int t = t_begin; t <= t_end; ++t) {
        float n0 = 0.f, n1 = 0.f;
        if (t < t_end) {
            n0 = emb[(t + 1) * KDIM + l];
            n1 = emb[(t + 1) * KDIM + l + 64];
        }

        float q0 = 0.f, q1 = 0.f;
        #pragma unroll
        for (int s = 0; s < 16; ++s) {
            const float4 w = *(const float4*)&pbuf[s * 8];
            const half2t p0 = __builtin_bit_cast(half2t, w.x);
            const half2t p1 = __builtin_bit_cast(half2t, w.y);
            const half2t p2 = __builtin_bit_cast(half2t, w.z);
            const half2t p3 = __builtin_bit_cast(half2t, w.w);
            q0 = dot2f(p0, Ea[4 * s + 0], q0);
            q0 = dot2f(p1, Ea[4 * s + 1], q0);
            q0 = dot2f(p2, Ea[4 * s + 2], q0);
            q0 = dot2f(p3, Ea[4 * s + 3], q0);
            q1 = dot2f(p0, Eb[4 * s + 0], q1);
            q1 = dot2f(p1, Eb[4 * s + 1], q1);
            q1 = dot2f(p2, Eb[4 * s + 2], q1);
            q1 = dot2f(p3, Eb[4 * s + 3], q1);
        }

        const float A0 = e0 + L + __logf(q0);
        const float A1 = e1 + L + __logf(q1);
        outb[t * KDIM + l] = A0;
        outb[t * KDIM + l + 64] = A1;
        if (t == len - 1) { la0 = A0; la1 = A1; }

        const float sigma = __shfl(q0, 0);
        const float ri = 1.0f / sigma;
        pbuf[l]      = (_Float16)(q0 * ri * __expf(e0));
        pbuf[l + 64] = (_Float16)(q1 * ri * __expf(e1));
        L += __logf(sigma);
        e0 = n0; e1 = n1;
    }

    const bool blockowns = (len == 1) ? (c == 0) : (((len - 2) >> 4) == c);
    if (blockowns) {
        float m2 = fmaxf(la0, la1);
        #pragma unroll
        for (int o = 32; o; o >>= 1) m2 = fmaxf(m2, __shfl_xor(m2, o));
        float e = __expf(la0 - m2) + __expf(la1 - m2);
        #pragma unroll
        for (int o = 32; o; o >>= 1) e += __shfl_xor(e, o);
        if (l == 0) logZ[b] = m2 + __logf(e);
    }
}

// ================= fallback (proven R1 kernel) for small ws =================
__global__ __launch_bounds__(256) void crf_forward_fallback(
    const float* __restrict__ trans, const float* __restrict__ em,
    const int* __restrict__ seq_lens, float* __restrict__ alpha_out,
    float* __restrict__ logZ_out)
{
    const int b = blockIdx.x;
    const int tid = threadIdx.x;
    const int j = tid & (KDIM - 1);
    const int h = tid >> 7;

    __shared__ __align__(16) float p_lds[KDIM];
    __shared__ float part[KDIM];
    __shared__ float red[8];

    float Ereg[64];
    #pragma unroll
    for (int k = 0; k < 64; ++k) Ereg[k] = __expf(trans[(h * 64 + k) * KDIM + j]);

    const int len = seq_lens[b];
    const float* emb = em + (size_t)b * TLEN * KDIM;
    float* outb = alpha_out + (size_t)b * TLEN * KDIM;

    float a = 0.f, last_a = 0.f;
    if (h == 0) {
        a = emb[j];
        outb[j] = a;
        if (len == 1) last_a = a;
    }
    for (int t = 1; t < TLEN; ++t) {
        {
            float v = (h == 0) ? a : -INFINITY;
            #pragma unroll
            for (int o = 32; o >= 1; o >>= 1) v = fmaxf(v, __shfl_xor(v, o));
            if ((tid & 63) == 0) red[tid >> 6] = v;
        }
        __syncthreads();
        const float m = fmaxf(red[0], red[1]);
        if (h == 0) p_lds[j] = __expf(a - m);
        __syncthreads();
        float em_t = 0.f;
        if (h == 0) em_t = emb[t * KDIM + j];
        float acc0 = 0.f, acc1 = 0.f, acc2 = 0.f, acc3 = 0.f;
        const float4* p4 = (const float4*)(p_lds + h * 64);
        #pragma unroll
        for (int k4 = 0; k4 < 16; ++k4) {
            float4 pv = p4[k4];
            acc0 = fmaf(pv.x, Ereg[4 * k4 + 0], acc0);
            acc1 = fmaf(pv.y, Ereg[4 * k4 + 1], acc1);
            acc2 = fmaf(pv.z, Ereg[4 * k4 + 2], acc2);
            acc3 = fmaf(pv.w, Ereg[4 * k4 + 3], acc3);
        }
        const float acc = (acc0 + acc1) + (acc2 + acc3);
        if (h == 1) part[j] = acc;
        __syncthreads();
        if (h == 0) {
            const float q = acc + part[j];
            a = em_t + m + __logf(q);
            outb[t * KDIM + j] = a;
            if (t == len - 1) last_a = a;
        }
    }
    {
        float v = (h == 0) ? last_a : -INFINITY;
        #pragma unroll
        for (int o = 32; o >= 1; o >>= 1) v = fmaxf(v, __shfl_xor(v, o));
        if ((tid & 63) == 0) red[tid >> 6] = v;
    }
    __syncthreads();
    const float m2 = fmaxf(red[0], red[1]);
    float e = (h == 0) ? __expf(last_a - m2) : 0.f;
    #pragma unroll
    for (int o = 32; o >= 1; o >>= 1) e += __shfl_xor(e, o);
    if ((tid & 63) == 0) red[4 + (tid >> 6)] = e;
    __syncthreads();
    if (tid == 0) logZ_out[b] = m2 + logf(red[4] + red[5]);
}

extern "C" void kernel_launch(void* const* d_in, const int* in_sizes, int n_in,
                              void* d_out, int out_size, void* d_ws, size_t ws_size,
                              hipStream_t stream) {
    const float* trans    = (const float*)d_in[0];   // K*K
    const float* em       = (const float*)d_in[1];   // B*T*K
    const int*   seq_lens = (const int*)d_in[2];     // B

    float* alpha_out = (float*)d_out;                            // B*T*K
    float* logZ_out  = alpha_out + (size_t)BATCH * TLEN * KDIM;  // B

    if (ws_size < (size_t)WS_NEED) {
        crf_forward_fallback<<<BATCH, 256, 0, stream>>>(trans, em, seq_lens,
                                                        alpha_out, logZ_out);
        return;
    }

    char* ws = (char*)d_ws;
    _Float16* Pst  = (_Float16*)(ws + WS_PST);
    float*    Slog = (float*)(ws + WS_SLOG);
    float*    aEnt = (float*)(ws + WS_AENT);

    crf_chunkmat5<<<dim3(NMAT, BATCH), 256, 0, stream>>>(trans, em, Pst, Slog);
    crf_scanw<<<BATCH, 64, 0, stream>>>(em, Pst, Slog, aEnt);
    crf_replayw<<<dim3(NCH, BATCH), 64, 0, stream>>>(trans, em, seq_lens, aEnt,
                                                     alpha_out, logZ_out);
}

// Round 13
// 166.338 us; speedup vs baseline: 1.2968x; 1.2968x over previous
//
#include <hip/hip_runtime.h>
#include <math.h>

#define KDIM 128
#define TLEN 512
#define BATCH 16
#define CH_L 16
#define NCH 32           // chunks per batch (replay)
#define NMAT 31          // chunk matrices: chunk c covers t in [16c+1, 16c+16]

typedef _Float16 half8 __attribute__((ext_vector_type(8)));
typedef _Float16 half4 __attribute__((ext_vector_type(4)));
typedef _Float16 half2t __attribute__((ext_vector_type(2)));
typedef float floatx4 __attribute__((ext_vector_type(4)));

#if defined(__has_builtin)
#if __has_builtin(__builtin_amdgcn_fdot2)
#define HAVE_FDOT2 1
#endif
#endif

static __device__ __forceinline__ float dot2f(half2t a, half2t b, float c) {
#ifdef HAVE_FDOT2
    return __builtin_amdgcn_fdot2(a, b, c, false);
#else
    return fmaf((float)a[0], (float)b[0], fmaf((float)a[1], (float)b[1], c));
#endif
}

// acc += dot(packed-f16 w (4 VGPRs = 8 halfs), half8 v)
static __device__ __forceinline__ float dot8(const half8 v, const float4 w, float acc) {
    const uint4 r = __builtin_bit_cast(uint4, v);
    acc = dot2f(__builtin_bit_cast(half2t, w.x), __builtin_bit_cast(half2t, r.x), acc);
    acc = dot2f(__builtin_bit_cast(half2t, w.y), __builtin_bit_cast(half2t, r.y), acc);
    acc = dot2f(__builtin_bit_cast(half2t, w.z), __builtin_bit_cast(half2t, r.z), acc);
    acc = dot2f(__builtin_bit_cast(half2t, w.w), __builtin_bit_cast(half2t, r.w), acc);
    return acc;
}

// async global->LDS, 16 B per lane; LDS dest = wave-uniform base + lane*16
static __device__ __forceinline__ void gload_lds16(const _Float16* g, _Float16* l) {
    __builtin_amdgcn_global_load_lds(
        (const __attribute__((address_space(1))) void*)g,
        (__attribute__((address_space(3))) void*)l, 16, 0, 0);
}

// ---------------- ws layout (bytes) ----------------
// PST : f16 [BATCH][NMAT] chunks; scan layout: 16B unit u' = (2K+h)*64 + l holds
//       P[enter=K*8+e][exit=2l+h], e=0..7  (lane l owns exit cols 2l, 2l+1)
#define WS_PST   0
#define WS_SLOG  16252928
#define WS_AENT  16254912
#define WS_NEED  16517056

// Frag conventions (validated R2-R12):
//  A-frag tile(mt,kt): lane(quad,lm) holds A[mt*16+lm][kt*32+quad*8 .. +8]
//  B-frag tile(kt,nt): lane(quad,lm) holds B[kt*32+quad*8 .. +8][nt*16+lm]
//  C/D  tile(mt,nt):   lane(quad,lm) reg q = C[mt*16+quad*4+q][nt*16+lm]
//  padded B layout halfs: bofs(k,n) = ((n>>4)*16 + (k>>3))*136 + (n&15)*8 + (k&7)
// E is UNSHIFTED exp(trans) (|trans|<~4.7 -> f16-safe; R11-validated).
// S bookkeeping: S = sum(mE) + sum(log rr).
// LESSON (R12): never hold >~120 VGPRs of state in a 256-thread kernel — the
// compiler's occupancy heuristic caps allocation and spills to scratch.

// ================= kernel 1: chunk products (R11 core, new store layout) =======
__global__ __launch_bounds__(256, 2) void crf_chunkmat4(
    const float* __restrict__ trans, const float* __restrict__ em,
    _Float16* __restrict__ Pst, float* __restrict__ Sout)
{
    const int c = blockIdx.x;     // 0..NMAT-1
    const int b = blockIdx.y;
    const int tid = threadIdx.x;
    const int w = tid >> 6, lane = tid & 63;
    const int quad = lane >> 4, lm = lane & 15;

    __shared__ __align__(16) _Float16 buf[17408];   // 34.8 KB padded B-layout
    __shared__ __align__(16) float gAll[16 * KDIM]; // 8 KB
    __shared__ float mE[16];
    __shared__ float slotV[4];

    const int t0 = c * CH_L + 1;
    const float* emb = em + (size_t)b * TLEN * KDIM;

    // A fragments (E^T) from L2-hot trans, loop-invariant: 8 half8 = 32 VGPRs
    half8 EA[2][4];
    #pragma unroll
    for (int r = 0; r < 2; ++r) {
        const int m = (2 * w + r) * 16 + lm;
        #pragma unroll
        for (int kt = 0; kt < 4; ++kt) {
            #pragma unroll
            for (int i = 0; i < 8; ++i) {
                EA[r][kt][i] = (_Float16)__expf(trans[(kt * 32 + quad * 8 + i) * KDIM + m]);
            }
        }
    }

    #pragma unroll
    for (int s = 0; s < 2; ++s) {
        int i4 = tid + s * 256;
        *(float4*)&gAll[i4 * 4] = *(const float4*)&emb[t0 * KDIM + i4 * 4];
    }
    __syncthreads();

    #pragma unroll
    for (int r2 = 0; r2 < 4; ++r2) {
        const int r = w * 4 + r2;
        float v = fmaxf(gAll[r * KDIM + lane], gAll[r * KDIM + 64 + lane]);
        #pragma unroll
        for (int o = 32; o; o >>= 1) v = fmaxf(v, __shfl_xor(v, o));
        if (lane == 0) mE[r] = v;
    }
    __syncthreads();

    #pragma unroll
    for (int s = 0; s < 8; ++s) {
        int idx = tid + s * 256;
        gAll[idx] = __expf(gAll[idx] - mE[idx >> 7]);
    }
    __syncthreads();

    for (int s = 0; s < 8; ++s) {
        int g = tid + s * 256;
        int row = g >> 4, nl = g & 15;
        int addr = row * 136 + nl * 8;
        int koct = row & 15;
        int n = (row >> 4) * 16 + nl;
        int j0 = koct * 8;
        const float* tr_ = &trans[n * KDIM + j0];
        const float* g0p = &gAll[j0];
        half8 o;
        #pragma unroll
        for (int x = 0; x < 8; ++x) o[x] = (_Float16)(__expf(tr_[x]) * g0p[x]);
        *(half8*)&buf[addr] = o;
    }
    float S = 0.f;
    if (tid == 0) {
        #pragma unroll
        for (int r = 0; r < 16; ++r) S += mE[r];
    }
    __syncthreads();

    floatx4 acc[2][8];

    for (int it = 1; it < 16; ++it) {
        #pragma unroll
        for (int r = 0; r < 2; ++r)
            #pragma unroll
            for (int nt = 0; nt < 8; ++nt)
                acc[r][nt] = (floatx4){0.f, 0.f, 0.f, 0.f};

        #pragma unroll
        for (int kt = 0; kt < 4; ++kt) {
            #pragma unroll
            for (int nt = 0; nt < 8; ++nt) {
                half8 bb = *(const half8*)&buf[(nt * 16 + kt * 4 + quad) * 136 + lm * 8];
                acc[0][nt] = __builtin_amdgcn_mfma_f32_16x16x32_f16(EA[0][kt], bb, acc[0][nt], 0, 0, 0);
                acc[1][nt] = __builtin_amdgcn_mfma_f32_16x16x32_f16(EA[1][kt], bb, acc[1][nt], 0, 0, 0);
            }
        }

        const float* gc = &gAll[it * KDIM];
        const float4 gr0 = *(const float4*)&gc[(2 * w + 0) * 16 + quad * 4];
        const float4 gr1 = *(const float4*)&gc[(2 * w + 1) * 16 + quad * 4];

        float lmax = 0.f;
        #pragma unroll
        for (int nt = 0; nt < 8; ++nt) {
            floatx4 v0 = acc[0][nt], v1 = acc[1][nt];
            float a0 = fmaxf(fmaxf(v0.x * gr0.x, v0.y * gr0.y), fmaxf(v0.z * gr0.z, v0.w * gr0.w));
            float a1 = fmaxf(fmaxf(v1.x * gr1.x, v1.y * gr1.y), fmaxf(v1.z * gr1.z, v1.w * gr1.w));
            lmax = fmaxf(lmax, fmaxf(a0, a1));
        }
        #pragma unroll
        for (int o = 32; o; o >>= 1) lmax = fmaxf(lmax, __shfl_xor(lmax, o));
        if (lane == 0) slotV[w] = lmax;
        __syncthreads();                                   // barrier 1

        const float rr = fmaxf(fmaxf(slotV[0], slotV[1]), fmaxf(slotV[2], slotV[3]));
        const float rinv = 1.0f / rr;
        if (tid == 0) S += __logf(rr);

        const float4 s0 = {gr0.x * rinv, gr0.y * rinv, gr0.z * rinv, gr0.w * rinv};
        const float4 s1 = {gr1.x * rinv, gr1.y * rinv, gr1.z * rinv, gr1.w * rinv};
        const int jlb = (quad & 1) * 4;
        #pragma unroll
        for (int r = 0; r < 2; ++r) {
            const int tr = 2 * w + r;
            const int kh = tr * 2 + (quad >> 1);
            const float4 sc = r ? s1 : s0;
            #pragma unroll
            for (int nt = 0; nt < 8; ++nt) {
                const floatx4 v = acc[r][nt];
                half4 o;
                o[0] = (_Float16)(v.x * sc.x);
                o[1] = (_Float16)(v.y * sc.y);
                o[2] = (_Float16)(v.z * sc.z);
                o[3] = (_Float16)(v.w * sc.w);
                *(half4*)&buf[(nt * 16 + kh) * 136 + lm * 8 + jlb] = o;
            }
        }
        __syncthreads();                                   // barrier 2
    }

    // --- store in scanw2 layout: unit u' = (2K+h)*64 + l  (coalesced 16B units) ---
    _Float16* Pc = Pst + ((size_t)(b * NMAT + c)) * 16384;
    for (int s = 0; s < 8; ++s) {
        int u = tid + s * 256;               // target unit index
        int l = u & 63;
        int rh = u >> 6;                     // 0..31
        int K = rh >> 1, h = rh & 1;
        int j = 2 * l + h;
        const int base = ((K >> 1) * 16 + (j >> 3)) * 136 + (K & 1) * 64 + (j & 7);
        half8 v;
        #pragma unroll
        for (int e = 0; e < 8; ++e) v[e] = buf[base + e * 8];
        *(half8*)&Pc[u * 8] = v;
    }
    if (tid == 0) Sout[b * NMAT + c] = S;
}

// ================= kernel 2: scanw2 — DMA-staged chunks, zero matrix VGPRs =====
// One wave per batch. Chunks double-buffered in LDS via global_load_lds (no
// register prefetch -> no spill). Lane l owns exit cols 2l, 2l+1; LDS reads at
// (r*64+l)*16 are bank-uniform (conflict-free). Sigma-lag math identical to R8.
__global__ __launch_bounds__(64, 1) void crf_scanw2(
    const float* __restrict__ em, const _Float16* __restrict__ Pst,
    const float* __restrict__ S, float* __restrict__ aEnter)
{
    const int b = blockIdx.x;
    const int lane = threadIdx.x;
    const int j0 = 2 * lane;

    __shared__ __align__(16) _Float16 Pbuf[2][16384];  // 64 KB double buffer
    __shared__ __align__(16) _Float16 pbuf[KDIM];
    __shared__ float Sl[NMAT];

    const _Float16* Pb = Pst + (size_t)b * NMAT * 16384;
    float* aeb = aEnter + (size_t)b * NCH * KDIM;

    // DMA chunk 0 -> Pbuf[0] (32 x 1KB)
    #pragma unroll
    for (int i = 0; i < 32; ++i)
        gload_lds16(Pb + i * 512 + lane * 8, &Pbuf[0][i * 512]);

    if (lane < NMAT) Sl[lane] = S[b * NMAT + lane];

    // init p from em[b,0,:]
    float2 a0 = *(const float2*)&em[(size_t)b * TLEN * KDIM + j0];
    float mx = fmaxf(a0.x, a0.y);
    #pragma unroll
    for (int o = 32; o; o >>= 1) mx = fmaxf(mx, __shfl_xor(mx, o));
    float L = mx;
    *(float2*)&aeb[j0] = a0;
    {
        half2t p2;
        p2[0] = (_Float16)__expf(a0.x - L);
        p2[1] = (_Float16)__expf(a0.y - L);
        ((half2t*)pbuf)[lane] = p2;
    }

    for (int c = 0; c < NMAT; ++c) {
        const int cb = c & 1, nb = cb ^ 1;

        // chunk c's DMA (issued last iteration) must be complete
        asm volatile("s_waitcnt vmcnt(0)" ::: "memory");

        // issue DMA for chunk c+1 (hidden behind this step's compute)
        if (c + 1 < NMAT) {
            const _Float16* src = Pb + (size_t)(c + 1) * 16384;
            #pragma unroll
            for (int i = 0; i < 32; ++i)
                gload_lds16(src + i * 512 + lane * 8, &Pbuf[nb][i * 512]);
        }

        // ---- matvec: q_j = sum_k p_k P[k][j], j = 2l (q0), 2l+1 (q1) ----
        float q0 = 0.f, q1 = 0.f;
        #pragma unroll
        for (int K = 0; K < 16; ++K) {
            const float4 w = *(const float4*)&pbuf[K * 8];   // packed f16 p[8K..8K+7]
            const half8 c0 = *(const half8*)&Pbuf[cb][((2 * K + 0) * 64 + lane) * 8];
            const half8 c1 = *(const half8*)&Pbuf[cb][((2 * K + 1) * 64 + lane) * 8];
            q0 = dot8(c0, w, q0);
            q1 = dot8(c1, w, q1);
        }

        const float s_c = Sl[c];
        const float sigma = __shfl(q0, 0);     // q at j=0
        const float base = L + s_c;
        float2 st;
        st.x = base + __logf(q0);
        st.y = base + __logf(q1);
        *(float2*)&aeb[(c + 1) * KDIM + j0] = st;
        const float ri = 1.0f / sigma;
        half2t p2;
        p2[0] = (_Float16)(q0 * ri);
        p2[1] = (_Float16)(q1 * ri);
        ((half2t*)pbuf)[lane] = p2;
        L = base + __logf(sigma);
    }
}

// ================= kernel 3: replayw — one wave per (chunk,batch) (R10) ========
__global__ __launch_bounds__(64, 1) void crf_replayw(
    const float* __restrict__ trans, const float* __restrict__ em,
    const int* __restrict__ seq_lens, const float* __restrict__ aEnter,
    float* __restrict__ alpha, float* __restrict__ logZ)
{
    const int c = blockIdx.x, b = blockIdx.y;
    const int l = threadIdx.x;

    __shared__ __align__(16) _Float16 pbuf[KDIM];

    half2t Ea[64], Eb[64];
    #pragma unroll
    for (int t2 = 0; t2 < 64; ++t2) {
        const float* r0 = &trans[(2 * t2) * KDIM];
        const float* r1 = &trans[(2 * t2 + 1) * KDIM];
        half2t ea, eb;
        ea[0] = (_Float16)__expf(r0[l]);
        ea[1] = (_Float16)__expf(r1[l]);
        eb[0] = (_Float16)__expf(r0[l + 64]);
        eb[1] = (_Float16)__expf(r1[l + 64]);
        Ea[t2] = ea;
        Eb[t2] = eb;
    }

    const int len = seq_lens[b];
    const float* emb = em + (size_t)b * TLEN * KDIM;
    float* outb = alpha + (size_t)b * TLEN * KDIM;
    const float* ae = aEnter + ((size_t)b * NCH + c) * KDIM;

    float a0 = ae[l], a1 = ae[l + 64];
    if (c == 0) {
        a0 = emb[l];
        a1 = emb[l + 64];
    }
    float mx = fmaxf(a0, a1);
    #pragma unroll
    for (int o = 32; o; o >>= 1) mx = fmaxf(mx, __shfl_xor(mx, o));
    float L = mx;
    pbuf[l]      = (_Float16)__expf(a0 - L);
    pbuf[l + 64] = (_Float16)__expf(a1 - L);

    float la0 = 0.f, la1 = -INFINITY;
    if (c == 0) {
        outb[l] = a0;
        outb[l + 64] = a1;
        if (len == 1) { la0 = a0; la1 = a1; }
    }

    const int t_begin = c * CH_L + 1;
    const int t_end = (c == NCH - 1) ? (TLEN - 1) : (c * CH_L + CH_L);

    float e0 = emb[t_begin * KDIM + l];
    float e1 = emb[t_begin * KDIM + l + 64];

    for (int t = t_begin; t <= t_end; ++t) {
        float n0 = 0.f, n1 = 0.f;
        if (t < t_end) {
            n0 = emb[(t + 1) * KDIM + l];
            n1 = emb[(t + 1) * KDIM + l + 64];
        }

        float q0 = 0.f, q1 = 0.f;
        #pragma unroll
        for (int s = 0; s < 16; ++s) {
            const float4 w = *(const float4*)&pbuf[s * 8];
            const half2t p0 = __builtin_bit_cast(half2t, w.x);
            const half2t p1 = __builtin_bit_cast(half2t, w.y);
            const half2t p2 = __builtin_bit_cast(half2t, w.z);
            const half2t p3 = __builtin_bit_cast(half2t, w.w);
            q0 = dot2f(p0, Ea[4 * s + 0], q0);
            q0 = dot2f(p1, Ea[4 * s + 1], q0);
            q0 = dot2f(p2, Ea[4 * s + 2], q0);
            q0 = dot2f(p3, Ea[4 * s + 3], q0);
            q1 = dot2f(p0, Eb[4 * s + 0], q1);
            q1 = dot2f(p1, Eb[4 * s + 1], q1);
            q1 = dot2f(p2, Eb[4 * s + 2], q1);
            q1 = dot2f(p3, Eb[4 * s + 3], q1);
        }

        const float A0 = e0 + L + __logf(q0);
        const float A1 = e1 + L + __logf(q1);
        outb[t * KDIM + l] = A0;
        outb[t * KDIM + l + 64] = A1;
        if (t == len - 1) { la0 = A0; la1 = A1; }

        const float sigma = __shfl(q0, 0);
        const float ri = 1.0f / sigma;
        pbuf[l]      = (_Float16)(q0 * ri * __expf(e0));
        pbuf[l + 64] = (_Float16)(q1 * ri * __expf(e1));
        L += __logf(sigma);
        e0 = n0; e1 = n1;
    }

    const bool blockowns = (len == 1) ? (c == 0) : (((len - 2) >> 4) == c);
    if (blockowns) {
        float m2 = fmaxf(la0, la1);
        #pragma unroll
        for (int o = 32; o; o >>= 1) m2 = fmaxf(m2, __shfl_xor(m2, o));
        float e = __expf(la0 - m2) + __expf(la1 - m2);
        #pragma unroll
        for (int o = 32; o; o >>= 1) e += __shfl_xor(e, o);
        if (l == 0) logZ[b] = m2 + __logf(e);
    }
}

// ================= fallback (proven R1 kernel) for small ws =================
__global__ __launch_bounds__(256) void crf_forward_fallback(
    const float* __restrict__ trans, const float* __restrict__ em,
    const int* __restrict__ seq_lens, float* __restrict__ alpha_out,
    float* __restrict__ logZ_out)
{
    const int b = blockIdx.x;
    const int tid = threadIdx.x;
    const int j = tid & (KDIM - 1);
    const int h = tid >> 7;

    __shared__ __align__(16) float p_lds[KDIM];
    __shared__ float part[KDIM];
    __shared__ float red[8];

    float Ereg[64];
    #pragma unroll
    for (int k = 0; k < 64; ++k) Ereg[k] = __expf(trans[(h * 64 + k) * KDIM + j]);

    const int len = seq_lens[b];
    const float* emb = em + (size_t)b * TLEN * KDIM;
    float* outb = alpha_out + (size_t)b * TLEN * KDIM;

    float a = 0.f, last_a = 0.f;
    if (h == 0) {
        a = emb[j];
        outb[j] = a;
        if (len == 1) last_a = a;
    }
    for (int t = 1; t < TLEN; ++t) {
        {
            float v = (h == 0) ? a : -INFINITY;
            #pragma unroll
            for (int o = 32; o >= 1; o >>= 1) v = fmaxf(v, __shfl_xor(v, o));
            if ((tid & 63) == 0) red[tid >> 6] = v;
        }
        __syncthreads();
        const float m = fmaxf(red[0], red[1]);
        if (h == 0) p_lds[j] = __expf(a - m);
        __syncthreads();
        float em_t = 0.f;
        if (h == 0) em_t = emb[t * KDIM + j];
        float acc0 = 0.f, acc1 = 0.f, acc2 = 0.f, acc3 = 0.f;
        const float4* p4 = (const float4*)(p_lds + h * 64);
        #pragma unroll
        for (int k4 = 0; k4 < 16; ++k4) {
            float4 pv = p4[k4];
            acc0 = fmaf(pv.x, Ereg[4 * k4 + 0], acc0);
            acc1 = fmaf(pv.y, Ereg[4 * k4 + 1], acc1);
            acc2 = fmaf(pv.z, Ereg[4 * k4 + 2], acc2);
            acc3 = fmaf(pv.w, Ereg[4 * k4 + 3], acc3);
        }
        const float acc = (acc0 + acc1) + (acc2 + acc3);
        if (h == 1) part[j] = acc;
        __syncthreads();
        if (h == 0) {
            const float q = acc + part[j];
            a = em_t + m + __logf(q);
            outb[t * KDIM + j] = a;
            if (t == len - 1) last_a = a;
        }
    }
    {
        float v = (h == 0) ? last_a : -INFINITY;
        #pragma unroll
        for (int o = 32; o >= 1; o >>= 1) v = fmaxf(v, __shfl_xor(v, o));
        if ((tid & 63) == 0) red[tid >> 6] = v;
    }
    __syncthreads();
    const float m2 = fmaxf(red[0], red[1]);
    float e = (h == 0) ? __expf(last_a - m2) : 0.f;
    #pragma unroll
    for (int o = 32; o >= 1; o >>= 1) e += __shfl_xor(e, o);
    if ((tid & 63) == 0) red[4 + (tid >> 6)] = e;
    __syncthreads();
    if (tid == 0) logZ_out[b] = m2 + logf(red[4] + red[5]);
}

extern "C" void kernel_launch(void* const* d_in, const int* in_sizes, int n_in,
                              void* d_out, int out_size, void* d_ws, size_t ws_size,
                              hipStream_t stream) {
    const float* trans    = (const float*)d_in[0];   // K*K
    const float* em       = (const float*)d_in[1];   // B*T*K
    const int*   seq_lens = (const int*)d_in[2];     // B

    float* alpha_out = (float*)d_out;                            // B*T*K
    float* logZ_out  = alpha_out + (size_t)BATCH * TLEN * KDIM;  // B

    if (ws_size < (size_t)WS_NEED) {
        crf_forward_fallback<<<BATCH, 256, 0, stream>>>(trans, em, seq_lens,
                                                        alpha_out, logZ_out);
        return;
    }

    char* ws = (char*)d_ws;
    _Float16* Pst  = (_Float16*)(ws + WS_PST);
    float*    Slog = (float*)(ws + WS_SLOG);
    float*    aEnt = (float*)(ws + WS_AENT);

    crf_chunkmat4<<<dim3(NMAT, BATCH), 256, 0, stream>>>(trans, em, Pst, Slog);
    crf_scanw2<<<BATCH, 64, 0, stream>>>(em, Pst, Slog, aEnt);
    crf_replayw<<<dim3(NCH, BATCH), 64, 0, stream>>>(trans, em, seq_lens, aEnt,
                                                     alpha_out, logZ_out);
}